// Round 3
// baseline (776.090 us; speedup 1.0000x reference)
//
#include <hip/hip_runtime.h>

#define B_    64
#define T_    256
#define TA_   255
#define OBS_  512
#define ACT_  32
#define LAT_  64
#define NB_   8
#define BS_   8
#define PHI_  512
#define BT_   16384
#define BTA_  16320
#define CH_   16
#define NCH_  16

// output layout (floats): latent | rho | predicted_latents | predicted_obs
#define RHO_OFF   1048576ULL
#define PL_OFF    67895296ULL
#define POBS_OFF  68943872ULL

__device__ const float HC_[6] = {1.f/120.f, 1.f/24.f, 1.f/6.f, 0.5f, 1.f, 1.f};

// ---------------- encoder: latent = obs @ W_enc + b_enc ----------------
// 64x64 output tile, K chunked by 64 through LDS. Per-lane (divergent)
// addresses everywhere -> vector loads (round-1 lesson: wave-uniform
// addresses become s_load and thrash the scalar cache at 33 MB).
__global__ __launch_bounds__(256) void enc_kernel(
    const float* __restrict__ obs, const float* __restrict__ W,
    const float* __restrict__ bias, float* __restrict__ latent)
{
    __shared__ float At[64][68];   // At[k][row], pad 68: read = 2-way (free)
    __shared__ float Wt[64][64];   // Wt[k][col]
    const int tid = threadIdx.x;
    const int c0 = (tid & 15) * 4;
    const int r0 = (tid >> 4) * 4;
    const int row0 = blockIdx.x * 64;

    float4 pa[4], pw[4];
    // prefetch chunk 0
#pragma unroll
    for (int j = 0; j < 4; ++j) {
        int ft = tid + j * 256;
        int k4 = ft & 15, r = ft >> 4;
        pa[j] = *(const float4*)(obs + (size_t)(row0 + r) * OBS_ + k4 * 4);
        int c4 = ft & 15, kk = ft >> 4;
        pw[j] = *(const float4*)(W + (size_t)kk * LAT_ + c4 * 4);
    }

    float acc[4][4];
    float4 bv = *(const float4*)(bias + c0);
#pragma unroll
    for (int i = 0; i < 4; ++i) {
        acc[i][0] = bv.x; acc[i][1] = bv.y; acc[i][2] = bv.z; acc[i][3] = bv.w;
    }

    for (int kc = 0; kc < OBS_; kc += 64) {
#pragma unroll
        for (int j = 0; j < 4; ++j) {
            int ft = tid + j * 256;
            int k4 = ft & 15, r = ft >> 4;
            At[k4 * 4 + 0][r] = pa[j].x;
            At[k4 * 4 + 1][r] = pa[j].y;
            At[k4 * 4 + 2][r] = pa[j].z;
            At[k4 * 4 + 3][r] = pa[j].w;
            int c4 = ft & 15, kk = ft >> 4;
            *(float4*)(&Wt[kk][c4 * 4]) = pw[j];
        }
        __syncthreads();
        if (kc + 64 < OBS_) {
            // prefetch next chunk while computing this one
#pragma unroll
            for (int j = 0; j < 4; ++j) {
                int ft = tid + j * 256;
                int k4 = ft & 15, r = ft >> 4;
                pa[j] = *(const float4*)(obs + (size_t)(row0 + r) * OBS_ + kc + 64 + k4 * 4);
                int c4 = ft & 15, kk = ft >> 4;
                pw[j] = *(const float4*)(W + (size_t)(kc + 64 + kk) * LAT_ + c4 * 4);
            }
        }
#pragma unroll 4
        for (int kk = 0; kk < 64; ++kk) {
            float4 a = *(const float4*)(&At[kk][r0]);
            float4 w = *(const float4*)(&Wt[kk][c0]);
            acc[0][0] = fmaf(a.x, w.x, acc[0][0]); acc[0][1] = fmaf(a.x, w.y, acc[0][1]);
            acc[0][2] = fmaf(a.x, w.z, acc[0][2]); acc[0][3] = fmaf(a.x, w.w, acc[0][3]);
            acc[1][0] = fmaf(a.y, w.x, acc[1][0]); acc[1][1] = fmaf(a.y, w.y, acc[1][1]);
            acc[1][2] = fmaf(a.y, w.z, acc[1][2]); acc[1][3] = fmaf(a.y, w.w, acc[1][3]);
            acc[2][0] = fmaf(a.z, w.x, acc[2][0]); acc[2][1] = fmaf(a.z, w.y, acc[2][1]);
            acc[2][2] = fmaf(a.z, w.z, acc[2][2]); acc[2][3] = fmaf(a.z, w.w, acc[2][3]);
            acc[3][0] = fmaf(a.w, w.x, acc[3][0]); acc[3][1] = fmaf(a.w, w.y, acc[3][1]);
            acc[3][2] = fmaf(a.w, w.z, acc[3][2]); acc[3][3] = fmaf(a.w, w.w, acc[3][3]);
        }
        __syncthreads();
    }
#pragma unroll
    for (int i = 0; i < 4; ++i)
        *(float4*)(latent + (size_t)(row0 + r0 + i) * LAT_ + c0) =
            make_float4(acc[i][0], acc[i][1], acc[i][2], acc[i][3]);
}

// ---------------- 8x8 matmul in registers ----------------
__device__ __forceinline__ void mm8(float* __restrict__ D,
                                    const float* __restrict__ X,
                                    const float* __restrict__ Y)
{
#pragma unroll
    for (int r = 0; r < 8; ++r)
#pragma unroll
        for (int c = 0; c < 8; ++c) {
            float s = 0.f;
#pragma unroll
            for (int q = 0; q < 8; ++q) s = fmaf(X[r * 8 + q], Y[q * 8 + c], s);
            D[r * 8 + c] = s;
        }
}

// ---------------- phi GEMM + expm, one 8x8 block per thread ----------------
// (256,2): live set after in-place transpose is ph[64]+P[64]+Tt[64]+addr
// ~= 170 VGPR -> fits the 256 cap, 2 waves/SIMD for latency hiding.
__global__ __launch_bounds__(256, 2) void phi_expm_kernel(
    const float* __restrict__ act, const float* __restrict__ Wp,
    const float* __restrict__ bp, float* __restrict__ out_blocks,
    float* __restrict__ rho, int use_ws)
{
    const int bt = blockIdx.x * 256 + threadIdx.x;
    const int k  = blockIdx.y;
    if (bt >= BTA_) return;

    float ph[64];
    {
        const float* bpp = bp + k * 64;
#pragma unroll
        for (int p = 0; p < 64; ++p) ph[p] = bpp[p];
    }
    const float4* arow4 = (const float4*)(act + (size_t)bt * ACT_);
    const float* wk = Wp + k * 64;
#pragma unroll
    for (int a4 = 0; a4 < ACT_ / 4; ++a4) {
        float4 av = arow4[a4];
        const float* wr = wk + (size_t)(a4 * 4) * PHI_;
#pragma unroll
        for (int p = 0; p < 64; ++p) ph[p] = fmaf(av.x, wr[p], ph[p]);
        wr += PHI_;
#pragma unroll
        for (int p = 0; p < 64; ++p) ph[p] = fmaf(av.y, wr[p], ph[p]);
        wr += PHI_;
#pragma unroll
        for (int p = 0; p < 64; ++p) ph[p] = fmaf(av.z, wr[p], ph[p]);
        wr += PHI_;
#pragma unroll
        for (int p = 0; p < 64; ++p) ph[p] = fmaf(av.w, wr[p], ph[p]);
    }

    // in-place scale+transpose: A = (M^T)/8 where M[r][c]=ph[c*8+r]
#pragma unroll
    for (int r = 0; r < 8; ++r) {
        ph[r * 9] *= 0.125f;
#pragma unroll
        for (int c = r + 1; c < 8; ++c) {
            float t = ph[r * 8 + c];
            ph[r * 8 + c] = 0.125f * ph[c * 8 + r];
            ph[c * 8 + r] = 0.125f * t;
        }
    }

    // degree-7 Taylor, Horner: P = A/7! + I/6!; then 6x (P = A*P + c I)
    float P[64], Tt[64];
#pragma unroll
    for (int i = 0; i < 64; ++i) P[i] = (1.f / 5040.f) * ph[i];
#pragma unroll
    for (int d = 0; d < 8; ++d) P[d * 9] += 1.f / 720.f;

    for (int it = 0; it < 3; ++it) {
        mm8(Tt, ph, P);
        float c0 = HC_[2 * it];
#pragma unroll
        for (int d = 0; d < 8; ++d) Tt[d * 9] += c0;
        mm8(P, ph, Tt);
        float c1 = HC_[2 * it + 1];
#pragma unroll
        for (int d = 0; d < 8; ++d) P[d * 9] += c1;
    }
    // 3 squarings: E = P^(2^3)
    for (int sq = 0; sq < 3; ++sq) {
        mm8(Tt, P, P);
#pragma unroll
        for (int i = 0; i < 64; ++i) P[i] = Tt[i];
    }

    if (use_ws) {
        float* dst = out_blocks + ((size_t)bt * NB_ + k) * 64;
#pragma unroll
        for (int i = 0; i < 16; ++i)
            ((float4*)dst)[i] = make_float4(P[4*i], P[4*i+1], P[4*i+2], P[4*i+3]);
    } else {
        float* base = rho + ((size_t)bt * LAT_ + k * BS_) * LAT_ + k * BS_;
#pragma unroll
        for (int r = 0; r < 8; ++r) {
            *(float4*)(base + (size_t)r * LAT_)     = make_float4(P[r*8+0], P[r*8+1], P[r*8+2], P[r*8+3]);
            *(float4*)(base + (size_t)r * LAT_ + 4) = make_float4(P[r*8+4], P[r*8+5], P[r*8+6], P[r*8+7]);
        }
    }
}

// ---------------- rho writer: zeros + block diagonal, fully coalesced ----------------
__global__ __launch_bounds__(256) void rho_write_kernel(
    const float* __restrict__ blocks, float* __restrict__ rho)
{
    size_t idx = (size_t)blockIdx.x * 256 + threadIdx.x;   // float4 index
    int c4 = (int)(idx & 15);
    size_t rowg = idx >> 4;
    int row = (int)(rowg & 63);
    size_t bt = rowg >> 6;
    int k = row >> 3, r = row & 7;
    float4 v = make_float4(0.f, 0.f, 0.f, 0.f);
    if ((c4 >> 1) == k)
        v = ((const float4*)(blocks + ((bt * 8 + (size_t)k) * 64 + (size_t)r * 8)))[c4 & 1];
    ((float4*)rho)[idx] = v;
}

__global__ __launch_bounds__(256) void zero_kernel(float4* __restrict__ p)
{
    p[(size_t)blockIdx.x * 256 + threadIdx.x] = make_float4(0.f, 0.f, 0.f, 0.f);
}

// ======== parallel scan over the recurrence h_{t+1} = h_t * M_t ========
// Phase A: per (b,k,chunk) local prefix products L_i = M_{t0}...M_{t0+i}
__global__ __launch_bounds__(256) void scan_local_kernel(
    const float* __restrict__ eb, float* __restrict__ pfx)
{
    const int tid = blockIdx.x * 256 + threadIdx.x;   // 8192 threads
    const int k = tid & 7;
    const int j = (tid >> 3) & 15;
    const int b = tid >> 7;
    const int t0 = j * CH_;
    const int cnt = (TA_ - t0 < CH_) ? (TA_ - t0) : CH_;   // 16 (15 for last)
    const float* src = eb  + ((size_t)(b * TA_ + t0) * 8 + k) * 64;
    float*       dst = pfx + ((size_t)(b * TA_ + t0) * 8 + k) * 64;

    float R[64];
#pragma unroll
    for (int q = 0; q < 16; ++q) ((float4*)R)[q] = ((const float4*)src)[q];
#pragma unroll
    for (int q = 0; q < 16; ++q) ((float4*)dst)[q] = ((const float4*)R)[q];

    for (int i = 1; i < cnt; ++i) {
        const float* mp = src + (size_t)i * 512;
        float M[64];
#pragma unroll
        for (int q = 0; q < 16; ++q) ((float4*)M)[q] = ((const float4*)mp)[q];
        // R = R * M, in place row-by-row (row r of output reads only row r of R)
#pragma unroll
        for (int r = 0; r < 8; ++r) {
            float tmp[8];
#pragma unroll
            for (int c = 0; c < 8; ++c) {
                float s = 0.f;
#pragma unroll
                for (int q = 0; q < 8; ++q) s = fmaf(R[r * 8 + q], M[q * 8 + c], s);
                tmp[c] = s;
            }
#pragma unroll
            for (int c = 0; c < 8; ++c) R[r * 8 + c] = tmp[c];
        }
        float* dp = dst + (size_t)i * 512;
#pragma unroll
        for (int q = 0; q < 16; ++q) ((float4*)dp)[q] = ((const float4*)R)[q];
    }
}

// Phase B: per (b,k) scan of chunk totals -> g_j = h0 * M_0..M_{16j-1}; pl[:,0]
__global__ __launch_bounds__(64) void scan_chunk_kernel(
    const float* __restrict__ latent, const float* __restrict__ pfx,
    float* __restrict__ gws, float* __restrict__ pl)
{
    const int tid = blockIdx.x * 64 + threadIdx.x;   // 512 threads
    const int k = tid & 7, b = tid >> 3;
    float g[8];
    const float* l0 = latent + (size_t)b * T_ * LAT_ + k * 8;
#pragma unroll
    for (int m = 0; m < 8; ++m) g[m] = l0[m];

    float* pl0 = pl + (size_t)b * T_ * LAT_ + k * 8;
    *(float4*)(pl0)     = make_float4(g[0], g[1], g[2], g[3]);
    *(float4*)(pl0 + 4) = make_float4(g[4], g[5], g[6], g[7]);

    float* gp = gws + ((size_t)(b * NCH_) * 8 + k) * 8;
    *(float4*)(gp)     = make_float4(g[0], g[1], g[2], g[3]);
    *(float4*)(gp + 4) = make_float4(g[4], g[5], g[6], g[7]);

    for (int j = 1; j < NCH_; ++j) {
        const float* cp = pfx + ((size_t)(b * TA_ + j * CH_ - 1) * 8 + k) * 64;
        float C[64];
#pragma unroll
        for (int q = 0; q < 16; ++q) ((float4*)C)[q] = ((const float4*)cp)[q];
        float ng[8];
#pragma unroll
        for (int m = 0; m < 8; ++m) {
            float s = 0.f;
#pragma unroll
            for (int l = 0; l < 8; ++l) s = fmaf(g[l], C[l * 8 + m], s);
            ng[m] = s;
        }
#pragma unroll
        for (int m = 0; m < 8; ++m) g[m] = ng[m];
        float* gq = gws + ((size_t)(b * NCH_ + j) * 8 + k) * 8;
        *(float4*)(gq)     = make_float4(g[0], g[1], g[2], g[3]);
        *(float4*)(gq + 4) = make_float4(g[4], g[5], g[6], g[7]);
    }
}

// Phase C: per (b,t,k): h_t = g_j * L_{j,i}  -> pl[b,t+1,k*8..]
__global__ __launch_bounds__(256) void scan_emit_kernel(
    const float* __restrict__ pfx, const float* __restrict__ gws,
    float* __restrict__ pl)
{
    const int tid = blockIdx.x * 256 + threadIdx.x;   // 130560 threads
    const int k = tid & 7;
    const int bt = tid >> 3;            // 0..16319
    const int b = bt / TA_;
    const int t = bt - b * TA_;
    const int j = t >> 4;               // CH_ = 16

    float g[8];
    const float* gp = gws + ((size_t)(b * NCH_ + j) * 8 + k) * 8;
    *(float4*)(g)     = *(const float4*)(gp);
    *(float4*)(g + 4) = *(const float4*)(gp + 4);

    const float* lp = pfx + ((size_t)bt * 8 + k) * 64;
    float L[64];
#pragma unroll
    for (int q = 0; q < 16; ++q) ((float4*)L)[q] = ((const float4*)lp)[q];

    float h[8];
#pragma unroll
    for (int m = 0; m < 8; ++m) {
        float s = 0.f;
#pragma unroll
        for (int l = 0; l < 8; ++l) s = fmaf(g[l], L[l * 8 + m], s);
        h[m] = s;
    }
    float* op = pl + ((size_t)b * T_ + t + 1) * LAT_ + k * 8;
    *(float4*)(op)     = make_float4(h[0], h[1], h[2], h[3]);
    *(float4*)(op + 4) = make_float4(h[4], h[5], h[6], h[7]);
}

// ---------------- sequential recurrence (fallback for small ws) ----------------
__device__ __forceinline__ void load_block8(float* __restrict__ dst,
                                            const float* __restrict__ p, int rs)
{
#pragma unroll
    for (int r = 0; r < 8; ++r) {
        float4 x = *(const float4*)(p + (size_t)r * rs);
        float4 y = *(const float4*)(p + (size_t)r * rs + 4);
        dst[r*8+0] = x.x; dst[r*8+1] = x.y; dst[r*8+2] = x.z; dst[r*8+3] = x.w;
        dst[r*8+4] = y.x; dst[r*8+5] = y.y; dst[r*8+6] = y.z; dst[r*8+7] = y.w;
    }
}

__global__ __launch_bounds__(64) void recur_kernel(
    const float* __restrict__ latent, const float* __restrict__ eb,
    int chainA, int chainB, int ts, int rs, float* __restrict__ pl)
{
    const int tid = blockIdx.x * 64 + threadIdx.x;   // 0..511
    const int b = tid >> 3, k = tid & 7;
    const float* e = eb + (size_t)b * (size_t)chainA + (size_t)k * (size_t)chainB;

    float h[8];
    const float* l0 = latent + (size_t)b * T_ * LAT_ + k * 8;
#pragma unroll
    for (int j = 0; j < 8; ++j) h[j] = l0[j];
    float* plp = pl + (size_t)b * T_ * LAT_ + k * 8;
    *(float4*)(plp)     = make_float4(h[0], h[1], h[2], h[3]);
    *(float4*)(plp + 4) = make_float4(h[4], h[5], h[6], h[7]);

    float eA[64], eB[64];
    load_block8(eA, e, rs);

#define STEP_(EBUF)                                                          \
    {                                                                        \
        float nh[8];                                                         \
        _Pragma("unroll")                                                    \
        for (int c = 0; c < 8; ++c) {                                        \
            float s = 0.f;                                                   \
            _Pragma("unroll")                                                \
            for (int r = 0; r < 8; ++r) s = fmaf(h[r], EBUF[r * 8 + c], s);  \
            nh[c] = s;                                                       \
        }                                                                    \
        plp += LAT_;                                                         \
        *(float4*)(plp)     = make_float4(nh[0], nh[1], nh[2], nh[3]);       \
        *(float4*)(plp + 4) = make_float4(nh[4], nh[5], nh[6], nh[7]);       \
        _Pragma("unroll")                                                    \
        for (int j = 0; j < 8; ++j) h[j] = nh[j];                            \
    }

    for (int t = 0; t < TA_; t += 2) {
        int tn = (t + 1 < TA_) ? t + 1 : TA_ - 1;
        load_block8(eB, e + (size_t)tn * ts, rs);
        STEP_(eA);
        if (t + 1 >= TA_) break;
        int tn2 = (t + 2 < TA_) ? t + 2 : TA_ - 1;
        load_block8(eA, e + (size_t)tn2 * ts, rs);
        STEP_(eB);
    }
#undef STEP_
}

// ---------------- decoder: pobs = pl @ W_dec + b_dec ----------------
// 64x64 tile, K=64 (single chunk). grid = (row tiles, col tiles).
__global__ __launch_bounds__(256) void dec_kernel(
    const float* __restrict__ pl, const float* __restrict__ W,
    const float* __restrict__ bias, float* __restrict__ out)
{
    __shared__ float At[64][68];   // pl^T tile
    __shared__ float Wt[64][64];
    const int tid = threadIdx.x;
    const int c0 = (tid & 15) * 4;
    const int r0 = (tid >> 4) * 4;
    const int row0 = blockIdx.x * 64;
    const int n0 = blockIdx.y * 64;

#pragma unroll
    for (int j = 0; j < 4; ++j) {
        int ft = tid + j * 256;
        int k4 = ft & 15, r = ft >> 4;
        float4 v = *(const float4*)(pl + (size_t)(row0 + r) * LAT_ + k4 * 4);
        At[k4 * 4 + 0][r] = v.x;
        At[k4 * 4 + 1][r] = v.y;
        At[k4 * 4 + 2][r] = v.z;
        At[k4 * 4 + 3][r] = v.w;
        int c4 = ft & 15, kk = ft >> 4;
        *(float4*)(&Wt[kk][c4 * 4]) =
            *(const float4*)(W + (size_t)kk * OBS_ + n0 + c4 * 4);
    }
    __syncthreads();

    float acc[4][4];
    float4 bv = *(const float4*)(bias + n0 + c0);
#pragma unroll
    for (int i = 0; i < 4; ++i) {
        acc[i][0] = bv.x; acc[i][1] = bv.y; acc[i][2] = bv.z; acc[i][3] = bv.w;
    }
#pragma unroll 4
    for (int kk = 0; kk < 64; ++kk) {
        float4 a = *(const float4*)(&At[kk][r0]);
        float4 w = *(const float4*)(&Wt[kk][c0]);
        acc[0][0] = fmaf(a.x, w.x, acc[0][0]); acc[0][1] = fmaf(a.x, w.y, acc[0][1]);
        acc[0][2] = fmaf(a.x, w.z, acc[0][2]); acc[0][3] = fmaf(a.x, w.w, acc[0][3]);
        acc[1][0] = fmaf(a.y, w.x, acc[1][0]); acc[1][1] = fmaf(a.y, w.y, acc[1][1]);
        acc[1][2] = fmaf(a.y, w.z, acc[1][2]); acc[1][3] = fmaf(a.y, w.w, acc[1][3]);
        acc[2][0] = fmaf(a.z, w.x, acc[2][0]); acc[2][1] = fmaf(a.z, w.y, acc[2][1]);
        acc[2][2] = fmaf(a.z, w.z, acc[2][2]); acc[2][3] = fmaf(a.z, w.w, acc[2][3]);
        acc[3][0] = fmaf(a.w, w.x, acc[3][0]); acc[3][1] = fmaf(a.w, w.y, acc[3][1]);
        acc[3][2] = fmaf(a.w, w.z, acc[3][2]); acc[3][3] = fmaf(a.w, w.w, acc[3][3]);
    }
#pragma unroll
    for (int i = 0; i < 4; ++i)
        *(float4*)(out + (size_t)(row0 + r0 + i) * OBS_ + n0 + c0) =
            make_float4(acc[i][0], acc[i][1], acc[i][2], acc[i][3]);
}

extern "C" void kernel_launch(void* const* d_in, const int* in_sizes, int n_in,
                              void* d_out, int out_size, void* d_ws, size_t ws_size,
                              hipStream_t stream)
{
    const float* obs  = (const float*)d_in[0];
    const float* act  = (const float*)d_in[1];
    const float* Wenc = (const float*)d_in[2];
    const float* benc = (const float*)d_in[3];
    const float* Wdec = (const float*)d_in[4];
    const float* bdec = (const float*)d_in[5];
    const float* Wphi = (const float*)d_in[6];
    const float* bphi = (const float*)d_in[7];

    float* out    = (float*)d_out;
    float* latent = out;
    float* rho    = out + RHO_OFF;
    float* pl     = out + PL_OFF;
    float* pobs   = out + POBS_OFF;

    const size_t eb_elems = (size_t)BTA_ * NB_ * 64;          // 8,355,840 floats
    const size_t need_ws   = eb_elems * sizeof(float);         // 33.4 MB
    const size_t need_scan = (2 * eb_elems + 512 * NCH_ * 8) * sizeof(float);  // 64 MB
    const bool use_ws   = (ws_size >= need_ws);
    const bool use_scan = (ws_size >= need_scan);
    float* eb  = (float*)d_ws;
    float* pfx = eb + eb_elems;
    float* gws = pfx + eb_elems;

    // 1) encoder
    hipLaunchKernelGGL(enc_kernel, dim3(BT_ / 64), dim3(256), 0, stream,
                       obs, Wenc, benc, latent);

    // 2) phi + expm
    if (!use_ws)
        hipLaunchKernelGGL(zero_kernel, dim3(66846720 / 1024), dim3(256), 0, stream,
                           (float4*)rho);
    hipLaunchKernelGGL(phi_expm_kernel, dim3((BTA_ + 255) / 256, NB_), dim3(256), 0, stream,
                       act, Wphi, bphi, eb, rho, (int)use_ws);

    // 3) recurrence
    if (use_scan) {
        hipLaunchKernelGGL(scan_local_kernel, dim3(8192 / 256), dim3(256), 0, stream,
                           eb, pfx);
        hipLaunchKernelGGL(scan_chunk_kernel, dim3(8), dim3(64), 0, stream,
                           latent, pfx, gws, pl);
        hipLaunchKernelGGL(scan_emit_kernel, dim3(BTA_ * NB_ / 256), dim3(256), 0, stream,
                           pfx, gws, pl);
    } else if (use_ws) {
        hipLaunchKernelGGL(recur_kernel, dim3(8), dim3(64), 0, stream,
                           latent, eb, TA_ * 512, 64, 512, 8, pl);
    } else {
        hipLaunchKernelGGL(recur_kernel, dim3(8), dim3(64), 0, stream,
                           latent, rho, TA_ * 4096, BS_ * LAT_ + BS_, 4096, LAT_, pl);
    }

    // 4) rho materialization (zeros + diagonal blocks)
    if (use_ws)
        hipLaunchKernelGGL(rho_write_kernel, dim3(66846720 / 1024), dim3(256), 0, stream,
                           eb, rho);

    // 5) decoder
    hipLaunchKernelGGL(dec_kernel, dim3(BT_ / 64, OBS_ / 64), dim3(256), 0, stream,
                       pl, Wdec, bdec, pobs);
}

// Round 4
// 523.860 us; speedup vs baseline: 1.4815x; 1.4815x over previous
//
#include <hip/hip_runtime.h>

#define B_    64
#define T_    256
#define TA_   255
#define OBS_  512
#define ACT_  32
#define LAT_  64
#define NB_   8
#define BS_   8
#define PHI_  512
#define BT_   16384
#define BTA_  16320
#define CH_   16
#define NCH_  16

// output layout (floats): latent | rho | predicted_latents | predicted_obs
#define RHO_OFF   1048576ULL
#define PL_OFF    67895296ULL
#define POBS_OFF  68943872ULL

// ---------------- encoder: latent = obs @ W_enc + b_enc ----------------
// 64x64 output tile, K chunked by 64 through LDS. Per-lane (divergent)
// addresses everywhere -> vector loads (round-1 lesson: wave-uniform
// addresses become s_load and thrash the scalar cache at 33 MB).
__global__ __launch_bounds__(256) void enc_kernel(
    const float* __restrict__ obs, const float* __restrict__ W,
    const float* __restrict__ bias, float* __restrict__ latent)
{
    __shared__ float At[64][68];   // At[k][row], pad 68: read = 2-way (free)
    __shared__ float Wt[64][64];   // Wt[k][col]
    const int tid = threadIdx.x;
    const int c0 = (tid & 15) * 4;
    const int r0 = (tid >> 4) * 4;
    const int row0 = blockIdx.x * 64;

    float4 pa[4], pw[4];
    // prefetch chunk 0
#pragma unroll
    for (int j = 0; j < 4; ++j) {
        int ft = tid + j * 256;
        int k4 = ft & 15, r = ft >> 4;
        pa[j] = *(const float4*)(obs + (size_t)(row0 + r) * OBS_ + k4 * 4);
        int c4 = ft & 15, kk = ft >> 4;
        pw[j] = *(const float4*)(W + (size_t)kk * LAT_ + c4 * 4);
    }

    float acc[4][4];
    float4 bv = *(const float4*)(bias + c0);
#pragma unroll
    for (int i = 0; i < 4; ++i) {
        acc[i][0] = bv.x; acc[i][1] = bv.y; acc[i][2] = bv.z; acc[i][3] = bv.w;
    }

    for (int kc = 0; kc < OBS_; kc += 64) {
#pragma unroll
        for (int j = 0; j < 4; ++j) {
            int ft = tid + j * 256;
            int k4 = ft & 15, r = ft >> 4;
            At[k4 * 4 + 0][r] = pa[j].x;
            At[k4 * 4 + 1][r] = pa[j].y;
            At[k4 * 4 + 2][r] = pa[j].z;
            At[k4 * 4 + 3][r] = pa[j].w;
            int c4 = ft & 15, kk = ft >> 4;
            *(float4*)(&Wt[kk][c4 * 4]) = pw[j];
        }
        __syncthreads();
        if (kc + 64 < OBS_) {
            // prefetch next chunk while computing this one
#pragma unroll
            for (int j = 0; j < 4; ++j) {
                int ft = tid + j * 256;
                int k4 = ft & 15, r = ft >> 4;
                pa[j] = *(const float4*)(obs + (size_t)(row0 + r) * OBS_ + kc + 64 + k4 * 4);
                int c4 = ft & 15, kk = ft >> 4;
                pw[j] = *(const float4*)(W + (size_t)(kc + 64 + kk) * LAT_ + c4 * 4);
            }
        }
#pragma unroll 4
        for (int kk = 0; kk < 64; ++kk) {
            float4 a = *(const float4*)(&At[kk][r0]);
            float4 w = *(const float4*)(&Wt[kk][c0]);
            acc[0][0] = fmaf(a.x, w.x, acc[0][0]); acc[0][1] = fmaf(a.x, w.y, acc[0][1]);
            acc[0][2] = fmaf(a.x, w.z, acc[0][2]); acc[0][3] = fmaf(a.x, w.w, acc[0][3]);
            acc[1][0] = fmaf(a.y, w.x, acc[1][0]); acc[1][1] = fmaf(a.y, w.y, acc[1][1]);
            acc[1][2] = fmaf(a.y, w.z, acc[1][2]); acc[1][3] = fmaf(a.y, w.w, acc[1][3]);
            acc[2][0] = fmaf(a.z, w.x, acc[2][0]); acc[2][1] = fmaf(a.z, w.y, acc[2][1]);
            acc[2][2] = fmaf(a.z, w.z, acc[2][2]); acc[2][3] = fmaf(a.z, w.w, acc[2][3]);
            acc[3][0] = fmaf(a.w, w.x, acc[3][0]); acc[3][1] = fmaf(a.w, w.y, acc[3][1]);
            acc[3][2] = fmaf(a.w, w.z, acc[3][2]); acc[3][3] = fmaf(a.w, w.w, acc[3][3]);
        }
        __syncthreads();
    }
#pragma unroll
    for (int i = 0; i < 4; ++i)
        *(float4*)(latent + (size_t)(row0 + r0 + i) * LAT_ + c0) =
            make_float4(acc[i][0], acc[i][1], acc[i][2], acc[i][3]);
}

// ---------------- 8x8 matmul in registers ----------------
__device__ __forceinline__ void mm8(float* __restrict__ D,
                                    const float* __restrict__ X,
                                    const float* __restrict__ Y)
{
#pragma unroll
    for (int r = 0; r < 8; ++r)
#pragma unroll
        for (int c = 0; c < 8; ++c) {
            float s = 0.f;
#pragma unroll
            for (int q = 0; q < 8; ++q) s = fmaf(X[r * 8 + q], Y[q * 8 + c], s);
            D[r * 8 + c] = s;
        }
}

// ---------------- phi GEMM + expm, one 8x8 block per thread ----------------
// Round-3 counters: VGPR=128 + 310 MB scratch traffic = spill-bound (300us).
// Fix: in-place Horner via RIGHT-multiply (P = P*A + cI; valid since A and
// p(A) commute; row r of P*A needs only row r of P) -> live set is A+P+row
// = ~145 regs during Horner, P+T = 128 during squarings (A dead). (256,1)
// so no allocator bucket below ~160 can force spills.
__global__ __launch_bounds__(256, 1) void phi_expm_kernel(
    const float* __restrict__ act, const float* __restrict__ Wp,
    const float* __restrict__ bp, float* __restrict__ out_blocks,
    float* __restrict__ rho, int use_ws)
{
    const int bt = blockIdx.x * 256 + threadIdx.x;
    const int k  = blockIdx.y;
    if (bt >= BTA_) return;

    float A[64];
    {
        const float* bpp = bp + k * 64;
#pragma unroll
        for (int p = 0; p < 64; ++p) A[p] = bpp[p];
    }
    const float4* arow4 = (const float4*)(act + (size_t)bt * ACT_);
    const float* wk = Wp + k * 64;
#pragma unroll
    for (int a4 = 0; a4 < ACT_ / 4; ++a4) {
        float4 av = arow4[a4];
        const float* wr = wk + (size_t)(a4 * 4) * PHI_;
#pragma unroll
        for (int p = 0; p < 64; ++p) A[p] = fmaf(av.x, wr[p], A[p]);
        wr += PHI_;
#pragma unroll
        for (int p = 0; p < 64; ++p) A[p] = fmaf(av.y, wr[p], A[p]);
        wr += PHI_;
#pragma unroll
        for (int p = 0; p < 64; ++p) A[p] = fmaf(av.z, wr[p], A[p]);
        wr += PHI_;
#pragma unroll
        for (int p = 0; p < 64; ++p) A[p] = fmaf(av.w, wr[p], A[p]);
    }

    // in-place scale+transpose: A <- (block^T)/8 (reference transposes blocks;
    // scaling-and-squaring with s=3)
#pragma unroll
    for (int r = 0; r < 8; ++r) {
        A[r * 9] *= 0.125f;
#pragma unroll
        for (int c = r + 1; c < 8; ++c) {
            float t = A[r * 8 + c];
            A[r * 8 + c] = 0.125f * A[c * 8 + r];
            A[c * 8 + r] = 0.125f * t;
        }
    }

    // degree-7 Taylor, Horner with right-multiply, P updated IN PLACE:
    // P = A/7! + I/6!; then 6x (P = P*A + c I), c = 1/120,1/24,1/6,1/2,1,1
    float P[64];
#pragma unroll
    for (int i = 0; i < 64; ++i) P[i] = (1.f / 5040.f) * A[i];
#pragma unroll
    for (int d = 0; d < 8; ++d) P[d * 9] += 1.f / 720.f;

    constexpr float COEF[6] = {1.f/120.f, 1.f/24.f, 1.f/6.f, 0.5f, 1.f, 1.f};
#pragma unroll
    for (int it = 0; it < 6; ++it) {
        const float coef = COEF[it];
#pragma unroll
        for (int r = 0; r < 8; ++r) {
            float t[8];
#pragma unroll
            for (int c = 0; c < 8; ++c) {
                float s = 0.f;
#pragma unroll
                for (int q = 0; q < 8; ++q) s = fmaf(P[r * 8 + q], A[q * 8 + c], s);
                t[c] = s;
            }
#pragma unroll
            for (int c = 0; c < 8; ++c) P[r * 8 + c] = t[c];
            P[r * 9] += coef;
        }
    }

    // 3 squarings, ping-pong (A is dead; T reuses its registers): result in T
    float T[64];
    mm8(T, P, P);
    mm8(P, T, T);
    mm8(T, P, P);

    if (use_ws) {
        float* dst = out_blocks + ((size_t)bt * NB_ + k) * 64;
#pragma unroll
        for (int i = 0; i < 16; ++i)
            ((float4*)dst)[i] = make_float4(T[4*i], T[4*i+1], T[4*i+2], T[4*i+3]);
    } else {
        float* base = rho + ((size_t)bt * LAT_ + k * BS_) * LAT_ + k * BS_;
#pragma unroll
        for (int r = 0; r < 8; ++r) {
            *(float4*)(base + (size_t)r * LAT_)     = make_float4(T[r*8+0], T[r*8+1], T[r*8+2], T[r*8+3]);
            *(float4*)(base + (size_t)r * LAT_ + 4) = make_float4(T[r*8+4], T[r*8+5], T[r*8+6], T[r*8+7]);
        }
    }
}

// ---------------- rho writer: zeros + block diagonal, fully coalesced ----------------
__global__ __launch_bounds__(256) void rho_write_kernel(
    const float* __restrict__ blocks, float* __restrict__ rho)
{
    size_t idx = (size_t)blockIdx.x * 256 + threadIdx.x;   // float4 index
    int c4 = (int)(idx & 15);
    size_t rowg = idx >> 4;
    int row = (int)(rowg & 63);
    size_t bt = rowg >> 6;
    int k = row >> 3, r = row & 7;
    float4 v = make_float4(0.f, 0.f, 0.f, 0.f);
    if ((c4 >> 1) == k)
        v = ((const float4*)(blocks + ((bt * 8 + (size_t)k) * 64 + (size_t)r * 8)))[c4 & 1];
    ((float4*)rho)[idx] = v;
}

__global__ __launch_bounds__(256) void zero_kernel(float4* __restrict__ p)
{
    p[(size_t)blockIdx.x * 256 + threadIdx.x] = make_float4(0.f, 0.f, 0.f, 0.f);
}

// ======== parallel scan over the recurrence h_{t+1} = h_t * M_t ========
// Phase A: per (b,k,chunk) local prefix products L_i = M_{t0}...M_{t0+i}
__global__ __launch_bounds__(256) void scan_local_kernel(
    const float* __restrict__ eb, float* __restrict__ pfx)
{
    const int tid = blockIdx.x * 256 + threadIdx.x;   // 8192 threads
    const int k = tid & 7;
    const int j = (tid >> 3) & 15;
    const int b = tid >> 7;
    const int t0 = j * CH_;
    const int cnt = (TA_ - t0 < CH_) ? (TA_ - t0) : CH_;   // 16 (15 for last)
    const float* src = eb  + ((size_t)(b * TA_ + t0) * 8 + k) * 64;
    float*       dst = pfx + ((size_t)(b * TA_ + t0) * 8 + k) * 64;

    float R[64];
#pragma unroll
    for (int q = 0; q < 16; ++q) ((float4*)R)[q] = ((const float4*)src)[q];
#pragma unroll
    for (int q = 0; q < 16; ++q) ((float4*)dst)[q] = ((const float4*)R)[q];

    for (int i = 1; i < cnt; ++i) {
        const float* mp = src + (size_t)i * 512;
        float M[64];
#pragma unroll
        for (int q = 0; q < 16; ++q) ((float4*)M)[q] = ((const float4*)mp)[q];
        // R = R * M, in place row-by-row (row r of output reads only row r of R)
#pragma unroll
        for (int r = 0; r < 8; ++r) {
            float tmp[8];
#pragma unroll
            for (int c = 0; c < 8; ++c) {
                float s = 0.f;
#pragma unroll
                for (int q = 0; q < 8; ++q) s = fmaf(R[r * 8 + q], M[q * 8 + c], s);
                tmp[c] = s;
            }
#pragma unroll
            for (int c = 0; c < 8; ++c) R[r * 8 + c] = tmp[c];
        }
        float* dp = dst + (size_t)i * 512;
#pragma unroll
        for (int q = 0; q < 16; ++q) ((float4*)dp)[q] = ((const float4*)R)[q];
    }
}

// Phase B: per (b,k) scan of chunk totals -> g_j = h0 * M_0..M_{16j-1}; pl[:,0]
__global__ __launch_bounds__(64) void scan_chunk_kernel(
    const float* __restrict__ latent, const float* __restrict__ pfx,
    float* __restrict__ gws, float* __restrict__ pl)
{
    const int tid = blockIdx.x * 64 + threadIdx.x;   // 512 threads
    const int k = tid & 7, b = tid >> 3;
    float g[8];
    const float* l0 = latent + (size_t)b * T_ * LAT_ + k * 8;
#pragma unroll
    for (int m = 0; m < 8; ++m) g[m] = l0[m];

    float* pl0 = pl + (size_t)b * T_ * LAT_ + k * 8;
    *(float4*)(pl0)     = make_float4(g[0], g[1], g[2], g[3]);
    *(float4*)(pl0 + 4) = make_float4(g[4], g[5], g[6], g[7]);

    float* gp = gws + ((size_t)(b * NCH_) * 8 + k) * 8;
    *(float4*)(gp)     = make_float4(g[0], g[1], g[2], g[3]);
    *(float4*)(gp + 4) = make_float4(g[4], g[5], g[6], g[7]);

    for (int j = 1; j < NCH_; ++j) {
        const float* cp = pfx + ((size_t)(b * TA_ + j * CH_ - 1) * 8 + k) * 64;
        float C[64];
#pragma unroll
        for (int q = 0; q < 16; ++q) ((float4*)C)[q] = ((const float4*)cp)[q];
        float ng[8];
#pragma unroll
        for (int m = 0; m < 8; ++m) {
            float s = 0.f;
#pragma unroll
            for (int l = 0; l < 8; ++l) s = fmaf(g[l], C[l * 8 + m], s);
            ng[m] = s;
        }
#pragma unroll
        for (int m = 0; m < 8; ++m) g[m] = ng[m];
        float* gq = gws + ((size_t)(b * NCH_ + j) * 8 + k) * 8;
        *(float4*)(gq)     = make_float4(g[0], g[1], g[2], g[3]);
        *(float4*)(gq + 4) = make_float4(g[4], g[5], g[6], g[7]);
    }
}

// Phase C: per (b,t,k): h_t = g_j * L_{j,i}  -> pl[b,t+1,k*8..]
__global__ __launch_bounds__(256) void scan_emit_kernel(
    const float* __restrict__ pfx, const float* __restrict__ gws,
    float* __restrict__ pl)
{
    const int tid = blockIdx.x * 256 + threadIdx.x;   // 130560 threads
    const int k = tid & 7;
    const int bt = tid >> 3;            // 0..16319
    const int b = bt / TA_;
    const int t = bt - b * TA_;
    const int j = t >> 4;               // CH_ = 16

    float g[8];
    const float* gp = gws + ((size_t)(b * NCH_ + j) * 8 + k) * 8;
    *(float4*)(g)     = *(const float4*)(gp);
    *(float4*)(g + 4) = *(const float4*)(gp + 4);

    const float* lp = pfx + ((size_t)bt * 8 + k) * 64;
    float L[64];
#pragma unroll
    for (int q = 0; q < 16; ++q) ((float4*)L)[q] = ((const float4*)lp)[q];

    float h[8];
#pragma unroll
    for (int m = 0; m < 8; ++m) {
        float s = 0.f;
#pragma unroll
        for (int l = 0; l < 8; ++l) s = fmaf(g[l], L[l * 8 + m], s);
        h[m] = s;
    }
    float* op = pl + ((size_t)b * T_ + t + 1) * LAT_ + k * 8;
    *(float4*)(op)     = make_float4(h[0], h[1], h[2], h[3]);
    *(float4*)(op + 4) = make_float4(h[4], h[5], h[6], h[7]);
}

// ---------------- sequential recurrence (fallback for small ws) ----------------
__device__ __forceinline__ void load_block8(float* __restrict__ dst,
                                            const float* __restrict__ p, int rs)
{
#pragma unroll
    for (int r = 0; r < 8; ++r) {
        float4 x = *(const float4*)(p + (size_t)r * rs);
        float4 y = *(const float4*)(p + (size_t)r * rs + 4);
        dst[r*8+0] = x.x; dst[r*8+1] = x.y; dst[r*8+2] = x.z; dst[r*8+3] = x.w;
        dst[r*8+4] = y.x; dst[r*8+5] = y.y; dst[r*8+6] = y.z; dst[r*8+7] = y.w;
    }
}

__global__ __launch_bounds__(64) void recur_kernel(
    const float* __restrict__ latent, const float* __restrict__ eb,
    int chainA, int chainB, int ts, int rs, float* __restrict__ pl)
{
    const int tid = blockIdx.x * 64 + threadIdx.x;   // 0..511
    const int b = tid >> 3, k = tid & 7;
    const float* e = eb + (size_t)b * (size_t)chainA + (size_t)k * (size_t)chainB;

    float h[8];
    const float* l0 = latent + (size_t)b * T_ * LAT_ + k * 8;
#pragma unroll
    for (int j = 0; j < 8; ++j) h[j] = l0[j];
    float* plp = pl + (size_t)b * T_ * LAT_ + k * 8;
    *(float4*)(plp)     = make_float4(h[0], h[1], h[2], h[3]);
    *(float4*)(plp + 4) = make_float4(h[4], h[5], h[6], h[7]);

    float eA[64], eB[64];
    load_block8(eA, e, rs);

#define STEP_(EBUF)                                                          \
    {                                                                        \
        float nh[8];                                                         \
        _Pragma("unroll")                                                    \
        for (int c = 0; c < 8; ++c) {                                        \
            float s = 0.f;                                                   \
            _Pragma("unroll")                                                \
            for (int r = 0; r < 8; ++r) s = fmaf(h[r], EBUF[r * 8 + c], s);  \
            nh[c] = s;                                                       \
        }                                                                    \
        plp += LAT_;                                                         \
        *(float4*)(plp)     = make_float4(nh[0], nh[1], nh[2], nh[3]);       \
        *(float4*)(plp + 4) = make_float4(nh[4], nh[5], nh[6], nh[7]);       \
        _Pragma("unroll")                                                    \
        for (int j = 0; j < 8; ++j) h[j] = nh[j];                            \
    }

    for (int t = 0; t < TA_; t += 2) {
        int tn = (t + 1 < TA_) ? t + 1 : TA_ - 1;
        load_block8(eB, e + (size_t)tn * ts, rs);
        STEP_(eA);
        if (t + 1 >= TA_) break;
        int tn2 = (t + 2 < TA_) ? t + 2 : TA_ - 1;
        load_block8(eA, e + (size_t)tn2 * ts, rs);
        STEP_(eB);
    }
#undef STEP_
}

// ---------------- decoder: pobs = pl @ W_dec + b_dec ----------------
// 64x64 tile, K=64 (single chunk). grid = (row tiles, col tiles).
__global__ __launch_bounds__(256) void dec_kernel(
    const float* __restrict__ pl, const float* __restrict__ W,
    const float* __restrict__ bias, float* __restrict__ out)
{
    __shared__ float At[64][68];   // pl^T tile
    __shared__ float Wt[64][64];
    const int tid = threadIdx.x;
    const int c0 = (tid & 15) * 4;
    const int r0 = (tid >> 4) * 4;
    const int row0 = blockIdx.x * 64;
    const int n0 = blockIdx.y * 64;

#pragma unroll
    for (int j = 0; j < 4; ++j) {
        int ft = tid + j * 256;
        int k4 = ft & 15, r = ft >> 4;
        float4 v = *(const float4*)(pl + (size_t)(row0 + r) * LAT_ + k4 * 4);
        At[k4 * 4 + 0][r] = v.x;
        At[k4 * 4 + 1][r] = v.y;
        At[k4 * 4 + 2][r] = v.z;
        At[k4 * 4 + 3][r] = v.w;
        int c4 = ft & 15, kk = ft >> 4;
        *(float4*)(&Wt[kk][c4 * 4]) =
            *(const float4*)(W + (size_t)kk * OBS_ + n0 + c4 * 4);
    }
    __syncthreads();

    float acc[4][4];
    float4 bv = *(const float4*)(bias + n0 + c0);
#pragma unroll
    for (int i = 0; i < 4; ++i) {
        acc[i][0] = bv.x; acc[i][1] = bv.y; acc[i][2] = bv.z; acc[i][3] = bv.w;
    }
#pragma unroll 4
    for (int kk = 0; kk < 64; ++kk) {
        float4 a = *(const float4*)(&At[kk][r0]);
        float4 w = *(const float4*)(&Wt[kk][c0]);
        acc[0][0] = fmaf(a.x, w.x, acc[0][0]); acc[0][1] = fmaf(a.x, w.y, acc[0][1]);
        acc[0][2] = fmaf(a.x, w.z, acc[0][2]); acc[0][3] = fmaf(a.x, w.w, acc[0][3]);
        acc[1][0] = fmaf(a.y, w.x, acc[1][0]); acc[1][1] = fmaf(a.y, w.y, acc[1][1]);
        acc[1][2] = fmaf(a.y, w.z, acc[1][2]); acc[1][3] = fmaf(a.y, w.w, acc[1][3]);
        acc[2][0] = fmaf(a.z, w.x, acc[2][0]); acc[2][1] = fmaf(a.z, w.y, acc[2][1]);
        acc[2][2] = fmaf(a.z, w.z, acc[2][2]); acc[2][3] = fmaf(a.z, w.w, acc[2][3]);
        acc[3][0] = fmaf(a.w, w.x, acc[3][0]); acc[3][1] = fmaf(a.w, w.y, acc[3][1]);
        acc[3][2] = fmaf(a.w, w.z, acc[3][2]); acc[3][3] = fmaf(a.w, w.w, acc[3][3]);
    }
#pragma unroll
    for (int i = 0; i < 4; ++i)
        *(float4*)(out + (size_t)(row0 + r0 + i) * OBS_ + n0 + c0) =
            make_float4(acc[i][0], acc[i][1], acc[i][2], acc[i][3]);
}

extern "C" void kernel_launch(void* const* d_in, const int* in_sizes, int n_in,
                              void* d_out, int out_size, void* d_ws, size_t ws_size,
                              hipStream_t stream)
{
    const float* obs  = (const float*)d_in[0];
    const float* act  = (const float*)d_in[1];
    const float* Wenc = (const float*)d_in[2];
    const float* benc = (const float*)d_in[3];
    const float* Wdec = (const float*)d_in[4];
    const float* bdec = (const float*)d_in[5];
    const float* Wphi = (const float*)d_in[6];
    const float* bphi = (const float*)d_in[7];

    float* out    = (float*)d_out;
    float* latent = out;
    float* rho    = out + RHO_OFF;
    float* pl     = out + PL_OFF;
    float* pobs   = out + POBS_OFF;

    const size_t eb_elems = (size_t)BTA_ * NB_ * 64;          // 8,355,840 floats
    const size_t need_ws   = eb_elems * sizeof(float);         // 33.4 MB
    const size_t need_scan = (2 * eb_elems + 512 * NCH_ * 8) * sizeof(float);  // 64 MB
    const bool use_ws   = (ws_size >= need_ws);
    const bool use_scan = (ws_size >= need_scan);
    float* eb  = (float*)d_ws;
    float* pfx = eb + eb_elems;
    float* gws = pfx + eb_elems;

    // 1) encoder
    hipLaunchKernelGGL(enc_kernel, dim3(BT_ / 64), dim3(256), 0, stream,
                       obs, Wenc, benc, latent);

    // 2) phi + expm
    if (!use_ws)
        hipLaunchKernelGGL(zero_kernel, dim3(66846720 / 1024), dim3(256), 0, stream,
                           (float4*)rho);
    hipLaunchKernelGGL(phi_expm_kernel, dim3((BTA_ + 255) / 256, NB_), dim3(256), 0, stream,
                       act, Wphi, bphi, eb, rho, (int)use_ws);

    // 3) recurrence
    if (use_scan) {
        hipLaunchKernelGGL(scan_local_kernel, dim3(8192 / 256), dim3(256), 0, stream,
                           eb, pfx);
        hipLaunchKernelGGL(scan_chunk_kernel, dim3(8), dim3(64), 0, stream,
                           latent, pfx, gws, pl);
        hipLaunchKernelGGL(scan_emit_kernel, dim3(BTA_ * NB_ / 256), dim3(256), 0, stream,
                           pfx, gws, pl);
    } else if (use_ws) {
        hipLaunchKernelGGL(recur_kernel, dim3(8), dim3(64), 0, stream,
                           latent, eb, TA_ * 512, 64, 512, 8, pl);
    } else {
        hipLaunchKernelGGL(recur_kernel, dim3(8), dim3(64), 0, stream,
                           latent, rho, TA_ * 4096, BS_ * LAT_ + BS_, 4096, LAT_, pl);
    }

    // 4) rho materialization (zeros + diagonal blocks)
    if (use_ws)
        hipLaunchKernelGGL(rho_write_kernel, dim3(66846720 / 1024), dim3(256), 0, stream,
                           eb, rho);

    // 5) decoder
    hipLaunchKernelGGL(dec_kernel, dim3(BT_ / 64, OBS_ / 64), dim3(256), 0, stream,
                       pl, Wdec, bdec, pobs);
}

// Round 5
// 499.164 us; speedup vs baseline: 1.5548x; 1.0495x over previous
//
#include <hip/hip_runtime.h>

#define B_    64
#define T_    256
#define TA_   255
#define OBS_  512
#define ACT_  32
#define LAT_  64
#define NB_   8
#define BS_   8
#define PHI_  512
#define BT_   16384
#define BTA_  16320
#define CH_   8
#define NCH_  32

// output layout (floats): latent | rho | predicted_latents | predicted_obs
#define RHO_OFF   1048576ULL
#define PL_OFF    67895296ULL
#define POBS_OFF  68943872ULL

// ---------------- encoder: latent = obs @ W_enc + b_enc ----------------
// 64x64 output tile, K chunked by 64 through LDS. Per-lane (divergent)
// addresses everywhere -> vector loads (round-1 lesson: wave-uniform
// addresses become s_load and thrash the scalar cache at 33 MB).
__global__ __launch_bounds__(256) void enc_kernel(
    const float* __restrict__ obs, const float* __restrict__ W,
    const float* __restrict__ bias, float* __restrict__ latent)
{
    __shared__ float At[64][68];   // At[k][row], pad 68: read = 2-way (free)
    __shared__ float Wt[64][64];   // Wt[k][col]
    const int tid = threadIdx.x;
    const int c0 = (tid & 15) * 4;
    const int r0 = (tid >> 4) * 4;
    const int row0 = blockIdx.x * 64;

    float4 pa[4], pw[4];
    // prefetch chunk 0
#pragma unroll
    for (int j = 0; j < 4; ++j) {
        int ft = tid + j * 256;
        int k4 = ft & 15, r = ft >> 4;
        pa[j] = *(const float4*)(obs + (size_t)(row0 + r) * OBS_ + k4 * 4);
        int c4 = ft & 15, kk = ft >> 4;
        pw[j] = *(const float4*)(W + (size_t)kk * LAT_ + c4 * 4);
    }

    float acc[4][4];
    float4 bv = *(const float4*)(bias + c0);
#pragma unroll
    for (int i = 0; i < 4; ++i) {
        acc[i][0] = bv.x; acc[i][1] = bv.y; acc[i][2] = bv.z; acc[i][3] = bv.w;
    }

    for (int kc = 0; kc < OBS_; kc += 64) {
#pragma unroll
        for (int j = 0; j < 4; ++j) {
            int ft = tid + j * 256;
            int k4 = ft & 15, r = ft >> 4;
            At[k4 * 4 + 0][r] = pa[j].x;
            At[k4 * 4 + 1][r] = pa[j].y;
            At[k4 * 4 + 2][r] = pa[j].z;
            At[k4 * 4 + 3][r] = pa[j].w;
            int c4 = ft & 15, kk = ft >> 4;
            *(float4*)(&Wt[kk][c4 * 4]) = pw[j];
        }
        __syncthreads();
        if (kc + 64 < OBS_) {
            // prefetch next chunk while computing this one
#pragma unroll
            for (int j = 0; j < 4; ++j) {
                int ft = tid + j * 256;
                int k4 = ft & 15, r = ft >> 4;
                pa[j] = *(const float4*)(obs + (size_t)(row0 + r) * OBS_ + kc + 64 + k4 * 4);
                int c4 = ft & 15, kk = ft >> 4;
                pw[j] = *(const float4*)(W + (size_t)(kc + 64 + kk) * LAT_ + c4 * 4);
            }
        }
#pragma unroll 4
        for (int kk = 0; kk < 64; ++kk) {
            float4 a = *(const float4*)(&At[kk][r0]);
            float4 w = *(const float4*)(&Wt[kk][c0]);
            acc[0][0] = fmaf(a.x, w.x, acc[0][0]); acc[0][1] = fmaf(a.x, w.y, acc[0][1]);
            acc[0][2] = fmaf(a.x, w.z, acc[0][2]); acc[0][3] = fmaf(a.x, w.w, acc[0][3]);
            acc[1][0] = fmaf(a.y, w.x, acc[1][0]); acc[1][1] = fmaf(a.y, w.y, acc[1][1]);
            acc[1][2] = fmaf(a.y, w.z, acc[1][2]); acc[1][3] = fmaf(a.y, w.w, acc[1][3]);
            acc[2][0] = fmaf(a.z, w.x, acc[2][0]); acc[2][1] = fmaf(a.z, w.y, acc[2][1]);
            acc[2][2] = fmaf(a.z, w.z, acc[2][2]); acc[2][3] = fmaf(a.z, w.w, acc[2][3]);
            acc[3][0] = fmaf(a.w, w.x, acc[3][0]); acc[3][1] = fmaf(a.w, w.y, acc[3][1]);
            acc[3][2] = fmaf(a.w, w.z, acc[3][2]); acc[3][3] = fmaf(a.w, w.w, acc[3][3]);
        }
        __syncthreads();
    }
#pragma unroll
    for (int i = 0; i < 4; ++i)
        *(float4*)(latent + (size_t)(row0 + r0 + i) * LAT_ + c0) =
            make_float4(acc[i][0], acc[i][1], acc[i][2], acc[i][3]);
}

// ---------------- 8x8 matmul in registers ----------------
__device__ __forceinline__ void mm8(float* __restrict__ D,
                                    const float* __restrict__ X,
                                    const float* __restrict__ Y)
{
#pragma unroll
    for (int r = 0; r < 8; ++r)
#pragma unroll
        for (int c = 0; c < 8; ++c) {
            float s = 0.f;
#pragma unroll
            for (int q = 0; q < 8; ++q) s = fmaf(X[r * 8 + q], Y[q * 8 + c], s);
            D[r * 8 + c] = s;
        }
}

// ---------------- phi GEMM + expm, one 8x8 block per thread ----------------
// In-place Horner via right-multiply (A and p(A) commute); live set
// A+P+row ~= 145 regs. (256,1) -> 512-VGPR cap, no spill bucket.
// R4 counters confirmed: 300us (spilled) -> off the top-5 (<60us).
__global__ __launch_bounds__(256, 1) void phi_expm_kernel(
    const float* __restrict__ act, const float* __restrict__ Wp,
    const float* __restrict__ bp, float* __restrict__ out_blocks,
    float* __restrict__ rho, int use_ws)
{
    const int bt = blockIdx.x * 256 + threadIdx.x;
    const int k  = blockIdx.y;
    if (bt >= BTA_) return;

    float A[64];
    {
        const float* bpp = bp + k * 64;
#pragma unroll
        for (int p = 0; p < 64; ++p) A[p] = bpp[p];
    }
    const float4* arow4 = (const float4*)(act + (size_t)bt * ACT_);
    const float* wk = Wp + k * 64;
#pragma unroll
    for (int a4 = 0; a4 < ACT_ / 4; ++a4) {
        float4 av = arow4[a4];
        const float* wr = wk + (size_t)(a4 * 4) * PHI_;
#pragma unroll
        for (int p = 0; p < 64; ++p) A[p] = fmaf(av.x, wr[p], A[p]);
        wr += PHI_;
#pragma unroll
        for (int p = 0; p < 64; ++p) A[p] = fmaf(av.y, wr[p], A[p]);
        wr += PHI_;
#pragma unroll
        for (int p = 0; p < 64; ++p) A[p] = fmaf(av.z, wr[p], A[p]);
        wr += PHI_;
#pragma unroll
        for (int p = 0; p < 64; ++p) A[p] = fmaf(av.w, wr[p], A[p]);
    }

    // in-place scale+transpose: A <- (block^T)/8 (reference transposes blocks;
    // scaling-and-squaring with s=3)
#pragma unroll
    for (int r = 0; r < 8; ++r) {
        A[r * 9] *= 0.125f;
#pragma unroll
        for (int c = r + 1; c < 8; ++c) {
            float t = A[r * 8 + c];
            A[r * 8 + c] = 0.125f * A[c * 8 + r];
            A[c * 8 + r] = 0.125f * t;
        }
    }

    // degree-7 Taylor, Horner with right-multiply, P updated IN PLACE:
    // P = A/7! + I/6!; then 6x (P = P*A + c I), c = 1/120,1/24,1/6,1/2,1,1
    float P[64];
#pragma unroll
    for (int i = 0; i < 64; ++i) P[i] = (1.f / 5040.f) * A[i];
#pragma unroll
    for (int d = 0; d < 8; ++d) P[d * 9] += 1.f / 720.f;

    constexpr float COEF[6] = {1.f/120.f, 1.f/24.f, 1.f/6.f, 0.5f, 1.f, 1.f};
#pragma unroll
    for (int it = 0; it < 6; ++it) {
        const float coef = COEF[it];
#pragma unroll
        for (int r = 0; r < 8; ++r) {
            float t[8];
#pragma unroll
            for (int c = 0; c < 8; ++c) {
                float s = 0.f;
#pragma unroll
                for (int q = 0; q < 8; ++q) s = fmaf(P[r * 8 + q], A[q * 8 + c], s);
                t[c] = s;
            }
#pragma unroll
            for (int c = 0; c < 8; ++c) P[r * 8 + c] = t[c];
            P[r * 9] += coef;
        }
    }

    // 3 squarings, ping-pong (A is dead; T reuses its registers): result in T
    float T[64];
    mm8(T, P, P);
    mm8(P, T, T);
    mm8(T, P, P);

    if (use_ws) {
        float* dst = out_blocks + ((size_t)bt * NB_ + k) * 64;
#pragma unroll
        for (int i = 0; i < 16; ++i)
            ((float4*)dst)[i] = make_float4(T[4*i], T[4*i+1], T[4*i+2], T[4*i+3]);
    } else {
        float* base = rho + ((size_t)bt * LAT_ + k * BS_) * LAT_ + k * BS_;
#pragma unroll
        for (int r = 0; r < 8; ++r) {
            *(float4*)(base + (size_t)r * LAT_)     = make_float4(T[r*8+0], T[r*8+1], T[r*8+2], T[r*8+3]);
            *(float4*)(base + (size_t)r * LAT_ + 4) = make_float4(T[r*8+4], T[r*8+5], T[r*8+6], T[r*8+7]);
        }
    }
}

// ---------------- rho writer: zeros + block diagonal, fully coalesced ----------------
__global__ __launch_bounds__(256) void rho_write_kernel(
    const float* __restrict__ blocks, float* __restrict__ rho)
{
    size_t idx = (size_t)blockIdx.x * 256 + threadIdx.x;   // float4 index
    int c4 = (int)(idx & 15);
    size_t rowg = idx >> 4;
    int row = (int)(rowg & 63);
    size_t bt = rowg >> 6;
    int k = row >> 3, r = row & 7;
    float4 v = make_float4(0.f, 0.f, 0.f, 0.f);
    if ((c4 >> 1) == k)
        v = ((const float4*)(blocks + ((bt * 8 + (size_t)k) * 64 + (size_t)r * 8)))[c4 & 1];
    ((float4*)rho)[idx] = v;
}

__global__ __launch_bounds__(256) void zero_kernel(float4* __restrict__ p)
{
    p[(size_t)blockIdx.x * 256 + threadIdx.x] = make_float4(0.f, 0.f, 0.f, 0.f);
}

// ======== parallel scan over the recurrence h_{t+1} = h_t * M_t ========
// Phase A: per (b,k,chunk) local prefix products L_i = M_{t0}...M_{t0+i}
// Round-4 theory: no launch_bounds -> 128-VGPR default cap vs ~150 live
// -> spills, at 32-CU occupancy -> the hidden ~300us. (128,1) lifts the
// cap to 512; CH=8 doubles thread count; cnt==8 path fully unrolled so
// loads schedule across iterations.
#define SL_BODY_(I)                                                           \
    {                                                                         \
        const float* mp = src + (size_t)(I) * 512;                            \
        float M[64];                                                          \
        _Pragma("unroll")                                                     \
        for (int q = 0; q < 16; ++q) ((float4*)M)[q] = ((const float4*)mp)[q];\
        _Pragma("unroll")                                                     \
        for (int r = 0; r < 8; ++r) {                                         \
            float tmp[8];                                                     \
            _Pragma("unroll")                                                 \
            for (int c = 0; c < 8; ++c) {                                     \
                float s = 0.f;                                                \
                _Pragma("unroll")                                             \
                for (int q = 0; q < 8; ++q)                                   \
                    s = fmaf(R[r * 8 + q], M[q * 8 + c], s);                  \
                tmp[c] = s;                                                   \
            }                                                                 \
            _Pragma("unroll")                                                 \
            for (int c = 0; c < 8; ++c) R[r * 8 + c] = tmp[c];                \
        }                                                                     \
        float* dp = dst + (size_t)(I) * 512;                                  \
        _Pragma("unroll")                                                     \
        for (int q = 0; q < 16; ++q) ((float4*)dp)[q] = ((const float4*)R)[q];\
    }

__global__ __launch_bounds__(128, 1) void scan_local_kernel(
    const float* __restrict__ eb, float* __restrict__ pfx)
{
    const int tid = blockIdx.x * 128 + threadIdx.x;   // 16384 threads
    const int k = tid & 7;
    const int j = (tid >> 3) & 31;
    const int b = tid >> 8;
    const int t0 = j * CH_;
    const int cnt = (TA_ - t0 < CH_) ? (TA_ - t0) : CH_;   // 8 (7 for last chunk)
    const float* src = eb  + ((size_t)(b * TA_ + t0) * 8 + k) * 64;
    float*       dst = pfx + ((size_t)(b * TA_ + t0) * 8 + k) * 64;

    float R[64];
#pragma unroll
    for (int q = 0; q < 16; ++q) ((float4*)R)[q] = ((const float4*)src)[q];
#pragma unroll
    for (int q = 0; q < 16; ++q) ((float4*)dst)[q] = ((const float4*)R)[q];

    if (cnt == CH_) {
#pragma unroll
        for (int i = 1; i < CH_; ++i) SL_BODY_(i);
    } else {
#pragma unroll
        for (int i = 1; i < CH_ - 1; ++i) SL_BODY_(i);   // cnt is always 7 here
    }
}
#undef SL_BODY_

// Phase B: per (b,k) scan of chunk totals -> g_j = h0 * M_0..M_{CH*j-1}; pl[:,0]
// (64,1): live C+Cn+g ~= 140 regs needs the 512 cap too. Next-chunk prefetch.
__global__ __launch_bounds__(64, 1) void scan_chunk_kernel(
    const float* __restrict__ latent, const float* __restrict__ pfx,
    float* __restrict__ gws, float* __restrict__ pl)
{
    const int tid = blockIdx.x * 64 + threadIdx.x;   // 512 threads
    const int k = tid & 7, b = tid >> 3;
    float g[8];
    const float* l0 = latent + (size_t)b * T_ * LAT_ + k * 8;
#pragma unroll
    for (int m = 0; m < 8; ++m) g[m] = l0[m];

    float* pl0 = pl + (size_t)b * T_ * LAT_ + k * 8;
    *(float4*)(pl0)     = make_float4(g[0], g[1], g[2], g[3]);
    *(float4*)(pl0 + 4) = make_float4(g[4], g[5], g[6], g[7]);

    float* gp = gws + ((size_t)(b * NCH_) * 8 + k) * 8;
    *(float4*)(gp)     = make_float4(g[0], g[1], g[2], g[3]);
    *(float4*)(gp + 4) = make_float4(g[4], g[5], g[6], g[7]);

    float C[64];
    {
        const float* cp = pfx + ((size_t)(b * TA_ + CH_ - 1) * 8 + k) * 64;
#pragma unroll
        for (int q = 0; q < 16; ++q) ((float4*)C)[q] = ((const float4*)cp)[q];
    }
    for (int j = 1; j < NCH_; ++j) {
        float Cn[64];
        if (j + 1 < NCH_) {
            const float* cp = pfx + ((size_t)(b * TA_ + (j + 1) * CH_ - 1) * 8 + k) * 64;
#pragma unroll
            for (int q = 0; q < 16; ++q) ((float4*)Cn)[q] = ((const float4*)cp)[q];
        }
        float ng[8];
#pragma unroll
        for (int m = 0; m < 8; ++m) {
            float s = 0.f;
#pragma unroll
            for (int l = 0; l < 8; ++l) s = fmaf(g[l], C[l * 8 + m], s);
            ng[m] = s;
        }
#pragma unroll
        for (int m = 0; m < 8; ++m) g[m] = ng[m];
        float* gq = gws + ((size_t)(b * NCH_ + j) * 8 + k) * 8;
        *(float4*)(gq)     = make_float4(g[0], g[1], g[2], g[3]);
        *(float4*)(gq + 4) = make_float4(g[4], g[5], g[6], g[7]);
#pragma unroll
        for (int q = 0; q < 64; ++q) C[q] = Cn[q];
    }
}

// Phase C: per (b,t,k): h_t = g_j * L_{j,i}  -> pl[b,t+1,k*8..]
__global__ __launch_bounds__(256, 1) void scan_emit_kernel(
    const float* __restrict__ pfx, const float* __restrict__ gws,
    float* __restrict__ pl)
{
    const int tid = blockIdx.x * 256 + threadIdx.x;   // 130560 threads
    const int k = tid & 7;
    const int bt = tid >> 3;            // 0..16319
    const int b = bt / TA_;
    const int t = bt - b * TA_;
    const int j = t >> 3;               // CH_ = 8

    float g[8];
    const float* gp = gws + ((size_t)(b * NCH_ + j) * 8 + k) * 8;
    *(float4*)(g)     = *(const float4*)(gp);
    *(float4*)(g + 4) = *(const float4*)(gp + 4);

    const float* lp = pfx + ((size_t)bt * 8 + k) * 64;
    float L[64];
#pragma unroll
    for (int q = 0; q < 16; ++q) ((float4*)L)[q] = ((const float4*)lp)[q];

    float h[8];
#pragma unroll
    for (int m = 0; m < 8; ++m) {
        float s = 0.f;
#pragma unroll
        for (int l = 0; l < 8; ++l) s = fmaf(g[l], L[l * 8 + m], s);
        h[m] = s;
    }
    float* op = pl + ((size_t)b * T_ + t + 1) * LAT_ + k * 8;
    *(float4*)(op)     = make_float4(h[0], h[1], h[2], h[3]);
    *(float4*)(op + 4) = make_float4(h[4], h[5], h[6], h[7]);
}

// ---------------- sequential recurrence (fallback for small ws) ----------------
__device__ __forceinline__ void load_block8(float* __restrict__ dst,
                                            const float* __restrict__ p, int rs)
{
#pragma unroll
    for (int r = 0; r < 8; ++r) {
        float4 x = *(const float4*)(p + (size_t)r * rs);
        float4 y = *(const float4*)(p + (size_t)r * rs + 4);
        dst[r*8+0] = x.x; dst[r*8+1] = x.y; dst[r*8+2] = x.z; dst[r*8+3] = x.w;
        dst[r*8+4] = y.x; dst[r*8+5] = y.y; dst[r*8+6] = y.z; dst[r*8+7] = y.w;
    }
}

__global__ __launch_bounds__(64) void recur_kernel(
    const float* __restrict__ latent, const float* __restrict__ eb,
    int chainA, int chainB, int ts, int rs, float* __restrict__ pl)
{
    const int tid = blockIdx.x * 64 + threadIdx.x;   // 0..511
    const int b = tid >> 3, k = tid & 7;
    const float* e = eb + (size_t)b * (size_t)chainA + (size_t)k * (size_t)chainB;

    float h[8];
    const float* l0 = latent + (size_t)b * T_ * LAT_ + k * 8;
#pragma unroll
    for (int j = 0; j < 8; ++j) h[j] = l0[j];
    float* plp = pl + (size_t)b * T_ * LAT_ + k * 8;
    *(float4*)(plp)     = make_float4(h[0], h[1], h[2], h[3]);
    *(float4*)(plp + 4) = make_float4(h[4], h[5], h[6], h[7]);

    float eA[64], eB[64];
    load_block8(eA, e, rs);

#define STEP_(EBUF)                                                          \
    {                                                                        \
        float nh[8];                                                         \
        _Pragma("unroll")                                                    \
        for (int c = 0; c < 8; ++c) {                                        \
            float s = 0.f;                                                   \
            _Pragma("unroll")                                                \
            for (int r = 0; r < 8; ++r) s = fmaf(h[r], EBUF[r * 8 + c], s);  \
            nh[c] = s;                                                       \
        }                                                                    \
        plp += LAT_;                                                         \
        *(float4*)(plp)     = make_float4(nh[0], nh[1], nh[2], nh[3]);       \
        *(float4*)(plp + 4) = make_float4(nh[4], nh[5], nh[6], nh[7]);       \
        _Pragma("unroll")                                                    \
        for (int j = 0; j < 8; ++j) h[j] = nh[j];                            \
    }

    for (int t = 0; t < TA_; t += 2) {
        int tn = (t + 1 < TA_) ? t + 1 : TA_ - 1;
        load_block8(eB, e + (size_t)tn * ts, rs);
        STEP_(eA);
        if (t + 1 >= TA_) break;
        int tn2 = (t + 2 < TA_) ? t + 2 : TA_ - 1;
        load_block8(eA, e + (size_t)tn2 * ts, rs);
        STEP_(eB);
    }
#undef STEP_
}

// ---------------- decoder: pobs = pl @ W_dec + b_dec ----------------
// 64x64 tile, K=64 (single chunk). grid = (row tiles, col tiles).
__global__ __launch_bounds__(256) void dec_kernel(
    const float* __restrict__ pl, const float* __restrict__ W,
    const float* __restrict__ bias, float* __restrict__ out)
{
    __shared__ float At[64][68];   // pl^T tile
    __shared__ float Wt[64][64];
    const int tid = threadIdx.x;
    const int c0 = (tid & 15) * 4;
    const int r0 = (tid >> 4) * 4;
    const int row0 = blockIdx.x * 64;
    const int n0 = blockIdx.y * 64;

#pragma unroll
    for (int j = 0; j < 4; ++j) {
        int ft = tid + j * 256;
        int k4 = ft & 15, r = ft >> 4;
        float4 v = *(const float4*)(pl + (size_t)(row0 + r) * LAT_ + k4 * 4);
        At[k4 * 4 + 0][r] = v.x;
        At[k4 * 4 + 1][r] = v.y;
        At[k4 * 4 + 2][r] = v.z;
        At[k4 * 4 + 3][r] = v.w;
        int c4 = ft & 15, kk = ft >> 4;
        *(float4*)(&Wt[kk][c4 * 4]) =
            *(const float4*)(W + (size_t)kk * OBS_ + n0 + c4 * 4);
    }
    __syncthreads();

    float acc[4][4];
    float4 bv = *(const float4*)(bias + n0 + c0);
#pragma unroll
    for (int i = 0; i < 4; ++i) {
        acc[i][0] = bv.x; acc[i][1] = bv.y; acc[i][2] = bv.z; acc[i][3] = bv.w;
    }
#pragma unroll 4
    for (int kk = 0; kk < 64; ++kk) {
        float4 a = *(const float4*)(&At[kk][r0]);
        float4 w = *(const float4*)(&Wt[kk][c0]);
        acc[0][0] = fmaf(a.x, w.x, acc[0][0]); acc[0][1] = fmaf(a.x, w.y, acc[0][1]);
        acc[0][2] = fmaf(a.x, w.z, acc[0][2]); acc[0][3] = fmaf(a.x, w.w, acc[0][3]);
        acc[1][0] = fmaf(a.y, w.x, acc[1][0]); acc[1][1] = fmaf(a.y, w.y, acc[1][1]);
        acc[1][2] = fmaf(a.y, w.z, acc[1][2]); acc[1][3] = fmaf(a.y, w.w, acc[1][3]);
        acc[2][0] = fmaf(a.z, w.x, acc[2][0]); acc[2][1] = fmaf(a.z, w.y, acc[2][1]);
        acc[2][2] = fmaf(a.z, w.z, acc[2][2]); acc[2][3] = fmaf(a.z, w.w, acc[2][3]);
        acc[3][0] = fmaf(a.w, w.x, acc[3][0]); acc[3][1] = fmaf(a.w, w.y, acc[3][1]);
        acc[3][2] = fmaf(a.w, w.z, acc[3][2]); acc[3][3] = fmaf(a.w, w.w, acc[3][3]);
    }
#pragma unroll
    for (int i = 0; i < 4; ++i)
        *(float4*)(out + (size_t)(row0 + r0 + i) * OBS_ + n0 + c0) =
            make_float4(acc[i][0], acc[i][1], acc[i][2], acc[i][3]);
}

extern "C" void kernel_launch(void* const* d_in, const int* in_sizes, int n_in,
                              void* d_out, int out_size, void* d_ws, size_t ws_size,
                              hipStream_t stream)
{
    const float* obs  = (const float*)d_in[0];
    const float* act  = (const float*)d_in[1];
    const float* Wenc = (const float*)d_in[2];
    const float* benc = (const float*)d_in[3];
    const float* Wdec = (const float*)d_in[4];
    const float* bdec = (const float*)d_in[5];
    const float* Wphi = (const float*)d_in[6];
    const float* bphi = (const float*)d_in[7];

    float* out    = (float*)d_out;
    float* latent = out;
    float* rho    = out + RHO_OFF;
    float* pl     = out + PL_OFF;
    float* pobs   = out + POBS_OFF;

    const size_t eb_elems = (size_t)BTA_ * NB_ * 64;          // 8,355,840 floats
    const size_t need_ws   = eb_elems * sizeof(float);         // 33.4 MB
    const size_t need_scan = (2 * eb_elems + 512 * NCH_ * 8) * sizeof(float);  // ~67 MB
    const bool use_ws   = (ws_size >= need_ws);
    const bool use_scan = (ws_size >= need_scan);
    float* eb  = (float*)d_ws;
    float* pfx = eb + eb_elems;
    float* gws = pfx + eb_elems;

    // 1) encoder
    hipLaunchKernelGGL(enc_kernel, dim3(BT_ / 64), dim3(256), 0, stream,
                       obs, Wenc, benc, latent);

    // 2) phi + expm
    if (!use_ws)
        hipLaunchKernelGGL(zero_kernel, dim3(66846720 / 1024), dim3(256), 0, stream,
                           (float4*)rho);
    hipLaunchKernelGGL(phi_expm_kernel, dim3((BTA_ + 255) / 256, NB_), dim3(256), 0, stream,
                       act, Wphi, bphi, eb, rho, (int)use_ws);

    // 3) recurrence
    if (use_scan) {
        hipLaunchKernelGGL(scan_local_kernel, dim3(16384 / 128), dim3(128), 0, stream,
                           eb, pfx);
        hipLaunchKernelGGL(scan_chunk_kernel, dim3(8), dim3(64), 0, stream,
                           latent, pfx, gws, pl);
        hipLaunchKernelGGL(scan_emit_kernel, dim3(BTA_ * NB_ / 256), dim3(256), 0, stream,
                           pfx, gws, pl);
    } else if (use_ws) {
        hipLaunchKernelGGL(recur_kernel, dim3(8), dim3(64), 0, stream,
                           latent, eb, TA_ * 512, 64, 512, 8, pl);
    } else {
        hipLaunchKernelGGL(recur_kernel, dim3(8), dim3(64), 0, stream,
                           latent, rho, TA_ * 4096, BS_ * LAT_ + BS_, 4096, LAT_, pl);
    }

    // 4) rho materialization (zeros + diagonal blocks)
    if (use_ws)
        hipLaunchKernelGGL(rho_write_kernel, dim3(66846720 / 1024), dim3(256), 0, stream,
                           eb, rho);

    // 5) decoder
    hipLaunchKernelGGL(dec_kernel, dim3(BT_ / 64, OBS_ / 64), dim3(256), 0, stream,
                       pl, Wdec, bdec, pobs);
}